// Round 6
// baseline (153.333 us; speedup 1.0000x reference)
//
#include <hip/hip_runtime.h>

typedef short s16x8 __attribute__((ext_vector_type(8)));
typedef float f32x4 __attribute__((ext_vector_type(4)));

__device__ inline unsigned short bf16_rn(float f) {
  unsigned int u = __float_as_uint(f);
  return (unsigned short)((u + 0x7FFFu + ((u >> 16) & 1u)) >> 16);
}
__device__ inline float bf16f(unsigned short h) {
  return __uint_as_float(((unsigned int)h) << 16);
}

// async global->LDS DMA, 16 B per lane; LDS dest = wave-uniform base + lane*16
typedef __attribute__((address_space(3))) unsigned int lds_u32_t;
typedef __attribute__((address_space(1))) const unsigned int g_u32_t;
__device__ __forceinline__ void gload_lds16(const void* g, void* l) {
  __builtin_amdgcn_global_load_lds((g_u32_t*)g, (lds_u32_t*)l, 16, 0, 0);
}

// ---------------------------------------------------------------------------
// Kernel 1: codebook -> 32-code tiles, XOR-swizzled hi/lo bf16 image + norms.
// Tile = 32 codes: [hi 32x128 ushort | lo 32x128 ushort] (16 KB). Row r
// stores 8-dim chunk c at slot c ^ (r & 15). COALESCED: 1 chunk per thread.
// ---------------------------------------------------------------------------
__global__ __launch_bounds__(256) void vq_convert_cb(const float* __restrict__ cb,
                                                     unsigned short* __restrict__ cbimg,
                                                     float* __restrict__ cbn) {
  int id = blockIdx.x * 256 + threadIdx.x;  // chunk id 0..16383
  int k = id >> 4, c = id & 15;             // code row, chunk
  const float* p = cb + (size_t)k * 128 + c * 8;
  float4 a = *(const float4*)p, b = *(const float4*)(p + 4);
  float v[8] = {a.x, a.y, a.z, a.w, b.x, b.y, b.z, b.w};
  unsigned int hw[4], lw[4];
  float nrm = 0.f;
#pragma unroll
  for (int i = 0; i < 4; ++i) {
    unsigned short h0 = bf16_rn(v[2 * i]), h1 = bf16_rn(v[2 * i + 1]);
    float r0 = v[2 * i] - bf16f(h0), r1 = v[2 * i + 1] - bf16f(h1);
    unsigned short l0 = bf16_rn(r0), l1 = bf16_rn(r1);
    hw[i] = (unsigned)h0 | ((unsigned)h1 << 16);
    lw[i] = (unsigned)l0 | ((unsigned)l1 << 16);
    nrm += v[2 * i] * v[2 * i] + v[2 * i + 1] * v[2 * i + 1];
  }
#pragma unroll
  for (int off = 1; off < 16; off <<= 1) nrm += __shfl_xor(nrm, off);  // 16 chunk-lanes, same row
  int cs = c ^ (k & 15);
  unsigned short* dh = cbimg + (size_t)(k >> 5) * 8192 + (k & 31) * 128 + cs * 8;
  *(uint4*)dh = make_uint4(hw[0], hw[1], hw[2], hw[3]);
  *(uint4*)(dh + 4096) = make_uint4(lw[0], lw[1], lw[2], lw[3]);
  if (c == 0) cbn[k] = nrm;
}

// ---------------------------------------------------------------------------
// Kernel 2: distance+argmin. Grid 1024 = 512 token-groups x 2 K-halves.
// Block = 4 waves; wave owns 32 tokens (A hi/lo in regs). Its half's 16
// 32-code tiles stream through 2x16KB dbuf LDS (async DMA); 3-pass
// split-bf16 MFMA; exact-float top-2 (d,k) per token -> cand uint4.
// LDS ~35 KB -> 4 blocks/CU.
// ---------------------------------------------------------------------------
__global__ __launch_bounds__(256) void vq_main(
    const float* __restrict__ xg, const unsigned short* __restrict__ cbimg,
    const float* __restrict__ cbn, uint4* __restrict__ cand) {
  __shared__ __attribute__((aligned(16))) unsigned short sB[2][8192];  // 2 x 16 KB
  __shared__ float sNorm[512];
  const int tid = threadIdx.x;
  const int wave = tid >> 6, lane = tid & 63;
  const int i0 = lane & 15, q = lane >> 4;
  const int half = blockIdx.x & 1;
  const int grp = blockIdx.x >> 1;
  const int tok0 = grp * 128 + wave * 32;
  const int kbase = half * 512;

  // ---- this half's norms -> LDS (2 KB) ----
  *(float2*)&sNorm[tid * 2] = *(const float2*)(cbn + kbase + tid * 2);

  // ---- load own 32 tokens, split fp32 -> bf16 hi + lo in-register ----
  s16x8 ahi[2][4], alo[2][4];
#pragma unroll
  for (int r = 0; r < 2; ++r)
#pragma unroll
    for (int kf = 0; kf < 4; ++kf) {
      const float* p = xg + (size_t)(tok0 + r * 16 + i0) * 128 + kf * 32 + q * 8;
      float4 a = *(const float4*)p, b = *(const float4*)(p + 4);
      float v[8] = {a.x, a.y, a.z, a.w, b.x, b.y, b.z, b.w};
      s16x8 h, l;
#pragma unroll
      for (int j = 0; j < 8; ++j) {
        unsigned short hh = bf16_rn(v[j]);
        float rr = v[j] - bf16f(hh);
        h[j] = (short)hh;
        l[j] = (short)bf16_rn(rr);
      }
      ahi[r][kf] = h;
      alo[r][kf] = l;
    }

  int boff[4][2];  // LDS ushort offsets (XOR de-swizzle)
#pragma unroll
  for (int ks = 0; ks < 4; ++ks)
#pragma unroll
    for (int c = 0; c < 2; ++c)
      boff[ks][c] = (c * 16 + i0) * 128 + (((ks * 4 + q) ^ i0) * 8);

  // ---- async stage tile 0 (4 x 4KB rows; wave slice = 1 KB each) ----
  const char* gbase = (const char*)cbimg + half * 262144;
  const int so = wave * 1024 + lane * 16;
  const int su = wave * 1024;
  {
    const char* g = gbase + so;
    char* l = (char*)&sB[0][0] + su;
#pragma unroll
    for (int i = 0; i < 4; ++i) gload_lds16(g + i * 4096, l + i * 4096);
  }

  float d1[2][4], d2[2][4];
  int k1[2][4], k2[2][4];
#pragma unroll
  for (int r = 0; r < 2; ++r)
#pragma unroll
    for (int g = 0; g < 4; ++g) {
      d1[r][g] = 3.4e38f; d2[r][g] = 3.4e38f; k1[r][g] = 0; k2[r][g] = 0;
    }
  __syncthreads();  // tile 0 + norms resident

  for (int t = 0; t < 16; ++t) {
    const int cur = t & 1;
    if (t < 15) {
      const char* g = gbase + (t + 1) * 16384 + so;
      char* l = (char*)&sB[1 - cur][0] + su;
#pragma unroll
      for (int i = 0; i < 4; ++i) gload_lds16(g + i * 4096, l + i * 4096);
    }
    f32x4 acc[2][2];
#pragma unroll
    for (int r = 0; r < 2; ++r)
#pragma unroll
      for (int c = 0; c < 2; ++c) acc[r][c] = (f32x4){0.f, 0.f, 0.f, 0.f};

#pragma unroll
    for (int ks = 0; ks < 4; ++ks) {
      s16x8 bhi[2], blo[2];
#pragma unroll
      for (int c = 0; c < 2; ++c) {
        bhi[c] = *(const s16x8*)&sB[cur][boff[ks][c]];
        blo[c] = *(const s16x8*)&sB[cur][boff[ks][c] + 4096];
      }
#pragma unroll
      for (int r = 0; r < 2; ++r)
#pragma unroll
        for (int c = 0; c < 2; ++c) {
          acc[r][c] = __builtin_amdgcn_mfma_f32_16x16x32_bf16(ahi[r][ks], bhi[c], acc[r][c], 0, 0, 0);
          acc[r][c] = __builtin_amdgcn_mfma_f32_16x16x32_bf16(ahi[r][ks], blo[c], acc[r][c], 0, 0, 0);
          acc[r][c] = __builtin_amdgcn_mfma_f32_16x16x32_bf16(alo[r][ks], bhi[c], acc[r][c], 0, 0, 0);
        }
    }
    // ---- exact top-2 update; k ascending => strict < keeps first-min ----
#pragma unroll
    for (int c = 0; c < 2; ++c) {
      int kl = t * 32 + c * 16 + i0;
      float cn = sNorm[kl];
      int kc = kbase + kl;
#pragma unroll
      for (int r = 0; r < 2; ++r)
#pragma unroll
        for (int g = 0; g < 4; ++g) {
          float dd = fmaf(-2.f, acc[r][c][g], cn);
          bool w = dd < d1[r][g];
          float ld = w ? d1[r][g] : dd;
          int lk = w ? k1[r][g] : kc;
          d1[r][g] = w ? dd : d1[r][g];
          k1[r][g] = w ? kc : k1[r][g];
          bool w2 = ld < d2[r][g];
          d2[r][g] = w2 ? ld : d2[r][g];
          k2[r][g] = w2 ? lk : k2[r][g];
        }
    }
    __syncthreads();
  }

  // ---- butterfly merge of top-2 across the 16 i0-lanes (lex d,k) ----
#pragma unroll
  for (int off = 1; off < 16; off <<= 1) {
#pragma unroll
    for (int r = 0; r < 2; ++r)
#pragma unroll
      for (int g = 0; g < 4; ++g) {
        float od1 = __shfl_xor(d1[r][g], off);
        int ok1 = __shfl_xor(k1[r][g], off);
        float od2 = __shfl_xor(d2[r][g], off);
        int ok2 = __shfl_xor(k2[r][g], off);
        bool t1 = (od1 < d1[r][g]) || (od1 == d1[r][g] && ok1 < k1[r][g]);
        float w1d = t1 ? od1 : d1[r][g];
        int w1k = t1 ? ok1 : k1[r][g];
        float l1d = t1 ? d1[r][g] : od1;
        int l1k = t1 ? k1[r][g] : ok1;
        float c2d = t1 ? od2 : d2[r][g];
        int c2k = t1 ? ok2 : k2[r][g];
        bool t2 = (l1d < c2d) || (l1d == c2d && l1k < c2k);
        d1[r][g] = w1d; k1[r][g] = w1k;
        d2[r][g] = t2 ? l1d : c2d;
        k2[r][g] = t2 ? l1k : c2k;
      }
  }

  if (i0 == 0) {
#pragma unroll
    for (int r = 0; r < 2; ++r)
#pragma unroll
      for (int g = 0; g < 4; ++g) {
        int token = tok0 + r * 16 + q * 4 + g;  // C-layout: row = q*4+g
        cand[(size_t)half * 65536 + token] =
            make_uint4(__float_as_uint(d1[r][g]), (unsigned)k1[r][g],
                       __float_as_uint(d2[r][g]), (unsigned)k2[r][g]);
      }
  }
}

// ---------------------------------------------------------------------------
// Kernel 3: merge halves. Approx-top-2 of 4 candidates, exact fp32 rescore,
// xq write, direct (non-atomic) loss store. Block = 128 tokens = 1 loss slot.
// ---------------------------------------------------------------------------
__global__ __launch_bounds__(256) void vq_merge(
    const float* __restrict__ xg, const float* __restrict__ cb,
    const uint4* __restrict__ cand, float* __restrict__ xq,
    float* __restrict__ loss) {
  __shared__ float sW[4];
  const int tid = threadIdx.x;
  const int l = tid & 15;
  float lacc = 0.f;
#pragma unroll
  for (int p = 0; p < 8; ++p) {
    int token = blockIdx.x * 128 + p * 16 + (tid >> 4);
    uint4 A = cand[token], B = cand[65536 + token];
    float a1 = __uint_as_float(A.x), a2 = __uint_as_float(A.z);
    float b1 = __uint_as_float(B.x), b2 = __uint_as_float(B.z);
    int ja1 = (int)A.y, ja2 = (int)A.w, jb1 = (int)B.y, jb2 = (int)B.w;
    // merge two sorted pairs -> approx top-2 (lex d,k)
    bool afirst = (a1 < b1) || (a1 == b1 && ja1 < jb1);
    int ka = afirst ? ja1 : jb1;
    float sd = afirst ? a2 : b2;
    int sk = afirst ? ja2 : jb2;
    float od = afirst ? b1 : a1;
    int ok = afirst ? jb1 : ja1;
    bool so_ = (od < sd) || (od == sd && ok < sk);
    int kb = so_ ? ok : sk;

    // exact fp32 rescore of {ka, kb}; lane l covers dims l*8..l*8+7
    const float* xp = xg + (size_t)token * 128 + l * 8;
    float4 xa = *(const float4*)xp, xb = *(const float4*)(xp + 4);
    const float* p1 = cb + (size_t)ka * 128 + l * 8;
    float4 ua = *(const float4*)p1, ub = *(const float4*)(p1 + 4);
    const float* p2 = cb + (size_t)kb * 128 + l * 8;
    float4 va = *(const float4*)p2, vb = *(const float4*)(p2 + 4);
    float xv[8] = {xa.x, xa.y, xa.z, xa.w, xb.x, xb.y, xb.z, xb.w};
    float e1[8] = {ua.x, ua.y, ua.z, ua.w, ub.x, ub.y, ub.z, ub.w};
    float e2[8] = {va.x, va.y, va.z, va.w, vb.x, vb.y, vb.z, vb.w};
    float s1 = 0.f, s2 = 0.f;
#pragma unroll
    for (int j = 0; j < 8; ++j) {
      float f1 = xv[j] - e1[j];
      float f2 = xv[j] - e2[j];
      s1 = fmaf(f1, f1, s1);
      s2 = fmaf(f2, f2, s2);
    }
#pragma unroll
    for (int off = 1; off < 16; off <<= 1) {
      s1 += __shfl_xor(s1, off);
      s2 += __shfl_xor(s2, off);
    }
    bool tk = (s2 < s1) || (s2 == s1 && kb < ka);
    float dwin = tk ? s2 : s1;
    float w[8];
#pragma unroll
    for (int j = 0; j < 8; ++j) w[j] = tk ? e2[j] : e1[j];
    float* op = xq + (size_t)token * 128 + l * 8;
    *(float4*)op = make_float4(w[0], w[1], w[2], w[3]);
    *(float4*)(op + 4) = make_float4(w[4], w[5], w[6], w[7]);
    if (l == 0) lacc += dwin;
  }
  // block reduce: only lanes with l==0 carry nonzero lacc
#pragma unroll
  for (int off = 1; off < 64; off <<= 1) lacc += __shfl_xor(lacc, off);
  if ((tid & 63) == 0) sW[tid >> 6] = lacc;
  __syncthreads();
  if (tid == 0)
    loss[blockIdx.x] = (sW[0] + sW[1] + sW[2] + sW[3]) * (1.25f / 16384.f);
}

// ---------------------------------------------------------------------------
extern "C" void kernel_launch(void* const* d_in, const int* in_sizes, int n_in,
                              void* d_out, int out_size, void* d_ws, size_t ws_size,
                              hipStream_t stream) {
  const float* x = (const float*)d_in[0];   // [8,64,128,128] fp32
  const float* cb = (const float*)d_in[1];  // [1024,128] fp32
  float* out = (float*)d_out;
  float* xq = out;
  float* loss = out + (size_t)8 * 64 * 128 * 128;  // 512 floats

  // ws: cbimg 512 KB | cbn 4 KB | cand 2 MB (16-B aligned)
  unsigned short* cbimg = (unsigned short*)d_ws;
  float* cbn = (float*)(cbimg + (size_t)1024 * 128 * 2);
  uint4* cand = (uint4*)(cbn + 1024);

  vq_convert_cb<<<64, 256, 0, stream>>>(cb, cbimg, cbn);
  vq_main<<<1024, 256, 0, stream>>>(x, cbimg, cbn, cand);
  vq_merge<<<512, 256, 0, stream>>>(x, cb, cand, xq, loss);
}